// Round 3
// baseline (647.978 us; speedup 1.0000x reference)
//
#include <hip/hip_runtime.h>

#define S_Q 2048
#define S_KV 2048
#define D_K 128
#define NH 64
// (1/sqrt(128)) * log2(e): fold softmax scale AND exp->exp2 conversion into Q
#define QSCALE 0.12751494907890272f

typedef __attribute__((ext_vector_type(8))) short s16x8;
typedef __attribute__((ext_vector_type(16))) float f32x16;

__device__ __attribute__((aligned(16))) unsigned short g_Kb[(size_t)NH * S_KV * D_K];
__device__ __attribute__((aligned(16))) unsigned short g_Vt[(size_t)NH * D_K * S_KV];

__device__ inline unsigned short f2bf(float f) {
  unsigned int u = __float_as_uint(f);
  u += 0x7FFFu + ((u >> 16) & 1u);  // RNE
  return (unsigned short)(u >> 16);
}

__device__ inline void plane32_swap(unsigned& a, unsigned& b) {
#if __has_builtin(__builtin_amdgcn_permlane32_swap)
  typedef unsigned __attribute__((ext_vector_type(2))) u32x2;
  u32x2 r = __builtin_amdgcn_permlane32_swap(a, b, false, false);
  a = r.x; b = r.y;
#else
  asm volatile("v_permlane32_swap_b32 %0, %1" : "+v"(a), "+v"(b));
#endif
}

// ---------------- merged prep: K->bf16 (bid<8192), V->bf16 transposed (bid>=8192) ----
__global__ __launch_bounds__(256) void prep_kernel(const float* __restrict__ K,
                                                   const float* __restrict__ V) {
  int bid = blockIdx.x;
  if (bid < 8192) {
    size_t g = (size_t)bid * 256 + threadIdx.x;
    const float* src = K + g * 8;
    float4 x = *(const float4*)src;
    float4 y = *(const float4*)(src + 4);
    union { uint4 q; unsigned short u[8]; } t;
    t.u[0] = f2bf(x.x); t.u[1] = f2bf(x.y); t.u[2] = f2bf(x.z); t.u[3] = f2bf(x.w);
    t.u[4] = f2bf(y.x); t.u[5] = f2bf(y.y); t.u[6] = f2bf(y.z); t.u[7] = f2bf(y.w);
    ((uint4*)g_Kb)[g] = t.q;
  } else {
    __shared__ float tile_f[64][33];
    bid -= 8192;
    int bh = bid >> 7;
    int rem = bid & 127;
    int t0 = (rem >> 2) << 6;
    int v0 = (rem & 3) << 5;
    int c = threadIdx.x & 31;
    int r8 = threadIdx.x >> 5;
#pragma unroll
    for (int i = 0; i < 8; i++) {
      int r = r8 + i * 8;
      tile_f[r][c] = V[((size_t)(bh * S_KV + t0 + r)) * D_K + v0 + c];
    }
    __syncthreads();
    int vv = threadIdx.x >> 3;
    int jc = threadIdx.x & 7;
    union { uint4 q; unsigned short u[8]; } t;
#pragma unroll
    for (int u8 = 0; u8 < 8; u8++) t.u[u8] = f2bf(tile_f[jc * 8 + u8][vv]);
    *(uint4*)&g_Vt[((size_t)(bh * D_K + v0 + vv)) * S_KV + t0 + jc * 8] = t.q;
  }
}

// ---------------- main: 128 thr = 2 waves x 32 q-rows; block = balanced pair of
// 64-row q-tiles (qj, 31-qj) -> every block exactly 68 kv-iterations ----------------
__global__ __launch_bounds__(128, 2) void attn_kernel(const float* __restrict__ Q,
                                                      const int* __restrict__ kpm,
                                                      float* __restrict__ out) {
  __shared__ unsigned short sK[2][32 * 136];   // [t=32][k=128] pitch 136
  __shared__ unsigned short sV[2][128 * 40];   // [v=128][t=32] pitch 40
  __shared__ unsigned sMask[64];

  const int bx = blockIdx.x;
  const int bh = ((bx & 7) << 3) | ((bx >> 3) & 7);  // same-bh blocks share XCD
  const int pair = bx >> 6;                          // 0..15
  const int tid = threadIdx.x;
  const int w = tid >> 6;           // wave 0/1
  const int ln = tid & 31;
  const int h = (tid >> 5) & 1;
  const int h8 = h * 8;
  const int b = bh >> 4;

  // ---- kpm ballot -> 64-word bitmask table (one-time) ----
#pragma unroll
  for (int rr = 0; rr < 16; rr++) {
    int idx = w * 1024 + rr * 64 + (tid & 63);
    unsigned long long bal = __ballot(kpm[b * S_KV + idx] != 0);
    if ((tid & 63) == 0) {
      sMask[w * 32 + rr * 2] = (unsigned)bal;
      sMask[w * 32 + rr * 2 + 1] = (unsigned)(bal >> 32);
    }
  }

  // ---- staging: 4 uint4 chunks each for K and V per thread ----
  int krr[4], kcc[4], vrr[4], vcc[4];
#pragma unroll
  for (int j = 0; j < 4; j++) {
    int id = tid + 128 * j;
    krr[j] = id >> 4; kcc[j] = (id & 15) * 8;
    vrr[j] = id >> 2; vcc[j] = (id & 3) * 8;
  }
  uint4 rk[4], rv[4];
  auto load_tile = [&](int t0) {
#pragma unroll
    for (int j = 0; j < 4; j++) {
      rk[j] = *(const uint4*)&g_Kb[((size_t)(bh * S_KV + t0 + krr[j])) * D_K + kcc[j]];
      rv[j] = *(const uint4*)&g_Vt[((size_t)(bh * D_K + vrr[j])) * S_KV + t0 + vcc[j]];
    }
  };
  auto store_tile = [&](int buf) {
#pragma unroll
    for (int j = 0; j < 4; j++) {
      *(uint4*)&sK[buf][krr[j] * 136 + kcc[j]] = rk[j];
      *(uint4*)&sV[buf][vrr[j] * 40 + vcc[j]] = rv[j];
    }
  };

  s16x8 ones;
  {
    union { s16x8 v; unsigned short u[8]; } t;
#pragma unroll
    for (int j = 0; j < 8; j++) t.u[j] = 0x3F80;
    ones = t.v;
  }

#pragma unroll 1
  for (int phase = 0; phase < 2; phase++) {
    const int qj = phase ? (31 - pair) : pair;
    const int qw = qj * 64 + w * 32;
    const int qln = qw + ln;

    // Q fragments (B-operand layout; scale*log2e folded)
    s16x8 qf[8];
    {
      const float* qrow = Q + ((size_t)(bh * S_Q + qln)) * D_K + h8;
#pragma unroll
      for (int kc = 0; kc < 8; kc++) {
        float4 x = *(const float4*)(qrow + kc * 16);
        float4 y = *(const float4*)(qrow + kc * 16 + 4);
        union { s16x8 v; unsigned short u[8]; } t;
        t.u[0] = f2bf(x.x * QSCALE); t.u[1] = f2bf(x.y * QSCALE);
        t.u[2] = f2bf(x.z * QSCALE); t.u[3] = f2bf(x.w * QSCALE);
        t.u[4] = f2bf(y.x * QSCALE); t.u[5] = f2bf(y.y * QSCALE);
        t.u[6] = f2bf(y.z * QSCALE); t.u[7] = f2bf(y.w * QSCALE);
        qf[kc] = t.v;
      }
    }

    f32x16 o[4] = {f32x16{}, f32x16{}, f32x16{}, f32x16{}};
    f32x16 sl = {};
    const int nT = qj * 2 + 2;

    load_tile(0);
    store_tile(0);
    if (nT > 1) load_tile(32);
    __syncthreads();  // buf0 (+ sMask on phase 0) ready

    for (int i = 0; i < nT; i++) {
      const int cur = i & 1;
      if (i + 1 < nT) {
        store_tile(1 - cur);
        if (i + 2 < nT) load_tile((i + 2) * 32);
      }
      const int t0 = i * 32;
      if (t0 <= qw + 31) {
        const unsigned km = sMask[i];
        // S^T = K * Q^T
        f32x16 sa = {};
#pragma unroll
        for (int kc = 0; kc < 8; kc++) {
          s16x8 kb = *(const s16x8*)&sK[cur][ln * 136 + kc * 16 + h8];
          sa = __builtin_amdgcn_mfma_f32_32x32x16_bf16(kb, qf[kc], sa, 0, 0, 0);
        }
        int thr = qln - t0;
        unsigned causal = (thr >= 31) ? 0xFFFFFFFFu : ((thr < 0) ? 0u : ((2u << thr) - 1u));
        unsigned pmh = (km & causal) >> (h * 4);
        float p[16];
#pragma unroll
        for (int r = 0; r < 16; r++) {
          const int tb = (r & 3) + 8 * (r >> 2);  // t_local = tb + 4h
          float e = __builtin_amdgcn_exp2f(sa[r]);
          p[r] = ((pmh >> tb) & 1u) ? e : 0.0f;
        }
        unsigned d[8];
#pragma unroll
        for (int m = 0; m < 4; m++) {
          d[2 * m] = __builtin_amdgcn_perm(__float_as_uint(p[4 * m + 1]),
                                           __float_as_uint(p[4 * m + 0]), 0x07060302u);
          d[2 * m + 1] = __builtin_amdgcn_perm(__float_as_uint(p[4 * m + 3]),
                                               __float_as_uint(p[4 * m + 2]), 0x07060302u);
        }
        plane32_swap(d[0], d[2]); plane32_swap(d[1], d[3]);
        plane32_swap(d[4], d[6]); plane32_swap(d[5], d[7]);
        union { unsigned u[4]; s16x8 v; } pu0, pu1;
        pu0.u[0] = d[0]; pu0.u[1] = d[1]; pu0.u[2] = d[2]; pu0.u[3] = d[3];
        pu1.u[0] = d[4]; pu1.u[1] = d[5]; pu1.u[2] = d[6]; pu1.u[3] = d[7];
        // O^T += V^T * P^T ; l via ones-MFMA (all regs/halves equal)
#pragma unroll
        for (int vt = 0; vt < 4; vt++) {
          s16x8 va = *(const s16x8*)&sV[cur][(vt * 32 + ln) * 40 + h8];
          s16x8 vb = *(const s16x8*)&sV[cur][(vt * 32 + ln) * 40 + 16 + h8];
          o[vt] = __builtin_amdgcn_mfma_f32_32x32x16_bf16(va, pu0.v, o[vt], 0, 0, 0);
          o[vt] = __builtin_amdgcn_mfma_f32_32x32x16_bf16(vb, pu1.v, o[vt], 0, 0, 0);
        }
        sl = __builtin_amdgcn_mfma_f32_32x32x16_bf16(ones, pu0.v, sl, 0, 0, 0);
        sl = __builtin_amdgcn_mfma_f32_32x32x16_bf16(ones, pu1.v, sl, 0, 0, 0);
      }
      __syncthreads();
    }

    // ---- epilogue (sl identical across regs and half-waves) ----
    float invl = 1.0f / sl[0];
    size_t orow = ((size_t)(bh * S_Q + qln)) * D_K;
#pragma unroll
    for (int vt = 0; vt < 4; vt++) {
#pragma unroll
      for (int qd = 0; qd < 4; qd++) {
        float4 vv;
        vv.x = o[vt][4 * qd + 0] * invl;
        vv.y = o[vt][4 * qd + 1] * invl;
        vv.z = o[vt][4 * qd + 2] * invl;
        vv.w = o[vt][4 * qd + 3] * invl;
        *(float4*)&out[orow + vt * 32 + qd * 8 + 4 * h] = vv;
      }
    }
  }
}

extern "C" void kernel_launch(void* const* d_in, const int* in_sizes, int n_in,
                              void* d_out, int out_size, void* d_ws, size_t ws_size,
                              hipStream_t stream) {
  const float* Q = (const float*)d_in[0];
  const float* K = (const float*)d_in[1];
  const float* V = (const float*)d_in[2];
  const int* kpm = (const int*)d_in[3];
  float* out = (float*)d_out;
  hipLaunchKernelGGL(prep_kernel, dim3(16384), dim3(256), 0, stream, K, V);
  hipLaunchKernelGGL(attn_kernel, dim3(1024), dim3(128), 0, stream, Q, kpm, out);
}

// Round 4
// 350.852 us; speedup vs baseline: 1.8469x; 1.8469x over previous
//
#include <hip/hip_runtime.h>

#define S_Q 2048
#define S_KV 2048
#define D_K 128
#define NH 64
// (1/sqrt(128)) * log2(e): fold softmax scale AND exp->exp2 conversion into Q
#define QSCALE 0.12751494907890272f

typedef __attribute__((ext_vector_type(8))) short s16x8;
typedef __attribute__((ext_vector_type(16))) float f32x16;

// Fragment-tiled bf16 K and V^T:
//   g_KbT[bh][tile][kc][lane*8 .. +8] : lane(ln,h) holds K[bh][tile*32+ln][kc*16+h*8+j]
//   g_VtT[bh][tile][c8][lane*8 .. +8] : c8=vt*2+hh, lane(ln,h) holds
//                                       V^T[vt*32+ln][tile*32 + hh*16 + h*8 + j]
// One 1KB chunk == one wave's ds-free b128 fragment load, perfectly coalesced.
__device__ __attribute__((aligned(16))) unsigned short g_KbT[(size_t)NH * 64 * 8 * 512];
__device__ __attribute__((aligned(16))) unsigned short g_VtT[(size_t)NH * 64 * 8 * 512];

__device__ inline unsigned short f2bf(float f) {
  unsigned int u = __float_as_uint(f);
  u += 0x7FFFu + ((u >> 16) & 1u);  // RNE
  return (unsigned short)(u >> 16);
}

__device__ inline void plane32_swap(unsigned& a, unsigned& b) {
#if __has_builtin(__builtin_amdgcn_permlane32_swap)
  typedef unsigned __attribute__((ext_vector_type(2))) u32x2;
  u32x2 r = __builtin_amdgcn_permlane32_swap(a, b, false, false);
  a = r.x; b = r.y;
#else
  asm volatile("v_permlane32_swap_b32 %0, %1" : "+v"(a), "+v"(b));
#endif
}

// ---------------- prep: fragment-tile K (bid<4096) and V (bid>=4096) ----------------
__global__ __launch_bounds__(256) void prep_kernel(const float* __restrict__ K,
                                                   const float* __restrict__ V) {
  __shared__ float smem[32 * 132];  // V branch: fp32 tile w/ pad; K branch aliases as bf16
  const int bid = blockIdx.x;
  const int tid = threadIdx.x;
  if (bid < 4096) {
    const int bh = bid >> 6, tile = bid & 63;
    unsigned short* sT = (unsigned short*)smem;  // [32][128] bf16, linear
    const float* src = K + ((size_t)(bh * S_KV + tile * 32)) * D_K + tid * 16;
    union { uint4 q; unsigned short u[8]; } t0, t1;
    float4 a0 = ((const float4*)src)[0], a1 = ((const float4*)src)[1];
    float4 a2 = ((const float4*)src)[2], a3 = ((const float4*)src)[3];
    t0.u[0] = f2bf(a0.x); t0.u[1] = f2bf(a0.y); t0.u[2] = f2bf(a0.z); t0.u[3] = f2bf(a0.w);
    t0.u[4] = f2bf(a1.x); t0.u[5] = f2bf(a1.y); t0.u[6] = f2bf(a1.z); t0.u[7] = f2bf(a1.w);
    t1.u[0] = f2bf(a2.x); t1.u[1] = f2bf(a2.y); t1.u[2] = f2bf(a2.z); t1.u[3] = f2bf(a2.w);
    t1.u[4] = f2bf(a3.x); t1.u[5] = f2bf(a3.y); t1.u[6] = f2bf(a3.z); t1.u[7] = f2bf(a3.w);
    *(uint4*)&sT[tid * 16] = t0.q;
    *(uint4*)&sT[tid * 16 + 8] = t1.q;
    __syncthreads();
    const size_t obase = (size_t)bid * 4096;
#pragma unroll
    for (int rep = 0; rep < 2; rep++) {
      int o = tid + rep * 256;
      int kc = o >> 6, l = o & 63, ln = l & 31, h = l >> 5;
      uint4 val = *(const uint4*)&sT[ln * 128 + kc * 16 + h * 8];
      *(uint4*)&g_KbT[obase + (size_t)kc * 512 + l * 8] = val;
    }
  } else {
    const int b2 = bid - 4096;
    const int bh = b2 >> 6, tile = b2 & 63;
    const float* src = V + ((size_t)(bh * S_KV + tile * 32)) * D_K + tid * 16;
    const int tr = (tid * 16) >> 7, vc = (tid * 16) & 127;
#pragma unroll
    for (int j = 0; j < 4; j++)
      *(float4*)&smem[tr * 132 + vc + 4 * j] = ((const float4*)src)[j];
    __syncthreads();
    const size_t obase = (size_t)b2 * 4096;
#pragma unroll
    for (int rep = 0; rep < 2; rep++) {
      int o = tid + rep * 256;
      int c8 = o >> 6, l = o & 63, ln = l & 31, h = l >> 5;
      int vt = c8 >> 1, hh = c8 & 1;
      union { uint4 q; unsigned short u[8]; } t;
#pragma unroll
      for (int j = 0; j < 8; j++)
        t.u[j] = f2bf(smem[(hh * 16 + h * 8 + j) * 132 + vt * 32 + ln]);
      *(uint4*)&g_VtT[obase + (size_t)c8 * 512 + l * 8] = t.q;
    }
  }
}

// ---------------- main: barrier-free flash attention, frags direct from L1/L2 ----------------
__global__ __launch_bounds__(256, 2) void attn_kernel(const float* __restrict__ Q,
                                                      const int* __restrict__ kpm,
                                                      float* __restrict__ out) {
  const int bx = blockIdx.x;
  const int bh = ((bx & 7) << 3) | ((bx >> 3) & 7);  // 16 q-blocks of one bh -> same XCD
  const int qp = bx >> 6;
  const int qi = (qp & 1) ? (qp >> 1) : (15 - (qp >> 1));  // interleave heavy/light (LPT-ish)
  const int tid = threadIdx.x;
  const int w = tid >> 6;
  const int l6 = tid & 63;
  const int ln = tid & 31;
  const int h = (tid >> 5) & 1;
  const int h8 = h * 8;
  const int qw = qi * 128 + w * 32;
  const int qln = qw + ln;
  const int b = bh >> 4;

  // Q fragments (B-operand layout; scale*log2e folded)
  s16x8 qf[8];
  {
    const float* qrow = Q + ((size_t)(bh * S_Q + qln)) * D_K + h8;
#pragma unroll
    for (int kc = 0; kc < 8; kc++) {
      float4 x = *(const float4*)(qrow + kc * 16);
      float4 y = *(const float4*)(qrow + kc * 16 + 4);
      union { s16x8 v; unsigned short u[8]; } t;
      t.u[0] = f2bf(x.x * QSCALE); t.u[1] = f2bf(x.y * QSCALE);
      t.u[2] = f2bf(x.z * QSCALE); t.u[3] = f2bf(x.w * QSCALE);
      t.u[4] = f2bf(y.x * QSCALE); t.u[5] = f2bf(y.y * QSCALE);
      t.u[6] = f2bf(y.z * QSCALE); t.u[7] = f2bf(y.w * QSCALE);
      qf[kc] = t.v;
    }
  }

  const unsigned short* Kb = g_KbT + (size_t)bh * 64 * 4096 + l6 * 8;
  const unsigned short* Vb = g_VtT + (size_t)bh * 64 * 4096 + l6 * 8;
  const int* kpmb = kpm + b * S_KV + ln;

  f32x16 o[4] = {f32x16{}, f32x16{}, f32x16{}, f32x16{}};
  float lsum = 0.0f;

  const int nI = qi * 4 + w + 1;  // this wave's causal extent; no wasted iters, no barriers
  for (int i = 0; i < nI; i++) {
    const int t0 = i * 32;
    unsigned long long bal = __ballot(kpmb[t0] != 0);  // lanes 32-63 duplicate 0-31
    const unsigned km = (unsigned)bal;

    // S^T = K * Q^T : 8 fragment loads straight from L1/L2
    const unsigned short* kt = Kb + (size_t)i * 4096;
    f32x16 sa = {};
#pragma unroll
    for (int kc = 0; kc < 8; kc++) {
      s16x8 kb = *(const s16x8*)(kt + kc * 512);
      sa = __builtin_amdgcn_mfma_f32_32x32x16_bf16(kb, qf[kc], sa, 0, 0, 0);
    }
    // combined causal + kpm mask for this lane's q-row
    int thr = qln - t0;
    unsigned causal = (thr >= 31) ? 0xFFFFFFFFu : ((thr < 0) ? 0u : ((2u << thr) - 1u));
    unsigned pmh = (km & causal) >> (h * 4);
    float p[16];
#pragma unroll
    for (int r = 0; r < 16; r++) {
      const int tb = (r & 3) + 8 * (r >> 2);  // t_local = tb + 4h
      float e = __builtin_amdgcn_exp2f(sa[r]);
      p[r] = ((pmh >> tb) & 1u) ? e : 0.0f;
      lsum += p[r];
    }
    // pack to bf16 dwords, half-wave swap -> P^T B-frags (verified R2 path)
    unsigned d[8];
#pragma unroll
    for (int m = 0; m < 4; m++) {
      d[2 * m] = __builtin_amdgcn_perm(__float_as_uint(p[4 * m + 1]),
                                       __float_as_uint(p[4 * m + 0]), 0x07060302u);
      d[2 * m + 1] = __builtin_amdgcn_perm(__float_as_uint(p[4 * m + 3]),
                                           __float_as_uint(p[4 * m + 2]), 0x07060302u);
    }
    plane32_swap(d[0], d[2]); plane32_swap(d[1], d[3]);
    plane32_swap(d[4], d[6]); plane32_swap(d[5], d[7]);
    union { unsigned u[4]; s16x8 v; } pu0, pu1;
    pu0.u[0] = d[0]; pu0.u[1] = d[1]; pu0.u[2] = d[2]; pu0.u[3] = d[3];
    pu1.u[0] = d[4]; pu1.u[1] = d[5]; pu1.u[2] = d[6]; pu1.u[3] = d[7];
    // O^T += V^T * P^T : 8 fragment loads straight from L1/L2
    const unsigned short* vtp = Vb + (size_t)i * 4096;
#pragma unroll
    for (int vt = 0; vt < 4; vt++) {
      s16x8 va = *(const s16x8*)(vtp + (vt * 2) * 512);
      s16x8 vb = *(const s16x8*)(vtp + (vt * 2 + 1) * 512);
      o[vt] = __builtin_amdgcn_mfma_f32_32x32x16_bf16(va, pu0.v, o[vt], 0, 0, 0);
      o[vt] = __builtin_amdgcn_mfma_f32_32x32x16_bf16(vb, pu1.v, o[vt], 0, 0, 0);
    }
  }

  // epilogue: halves hold disjoint t-columns -> one shfl to combine l
  float ltot = lsum + __shfl_xor(lsum, 32, 64);
  float invl = 1.0f / ltot;
  size_t orow = ((size_t)(bh * S_Q + qln)) * D_K;
#pragma unroll
  for (int vt = 0; vt < 4; vt++) {
#pragma unroll
    for (int qd = 0; qd < 4; qd++) {
      float4 vv;
      vv.x = o[vt][4 * qd + 0] * invl;
      vv.y = o[vt][4 * qd + 1] * invl;
      vv.z = o[vt][4 * qd + 2] * invl;
      vv.w = o[vt][4 * qd + 3] * invl;
      *(float4*)&out[orow + vt * 32 + qd * 8 + 4 * h] = vv;
    }
  }
}

extern "C" void kernel_launch(void* const* d_in, const int* in_sizes, int n_in,
                              void* d_out, int out_size, void* d_ws, size_t ws_size,
                              hipStream_t stream) {
  const float* Q = (const float*)d_in[0];
  const float* K = (const float*)d_in[1];
  const float* V = (const float*)d_in[2];
  const int* kpm = (const int*)d_in[3];
  float* out = (float*)d_out;
  hipLaunchKernelGGL(prep_kernel, dim3(8192), dim3(256), 0, stream, K, V);
  hipLaunchKernelGGL(attn_kernel, dim3(1024), dim3(256), 0, stream, Q, kpm, out);
}